// Round 1
// baseline (86.045 us; speedup 1.0000x reference)
//
#include <hip/hip_runtime.h>

// Problem constants (from reference): N = 9600 rows, D = 128, K = 16.
// out = sum(h*h) - ||h^T F||_F^2,  M = h^T F is [128 x 16] = 2048 floats.
//
// ws layout (floats): [0 .. 2047] = M (row-major d*16+k), [2048] = ssq.

#define GA 240  // blocks for the partial kernel (multiple of 8 XCDs)

__global__ __launch_bounds__(256) void kmeans_partial(
    const float* __restrict__ h, const float* __restrict__ F,
    float* __restrict__ ws, int N) {
    const int t  = threadIdx.x;
    const int k  = t & 15;    // cluster column 0..15
    const int dg = t >> 4;    // d-group 0..15, covers d = dg*8 .. dg*8+7

    float acc[8] = {0.f, 0.f, 0.f, 0.f, 0.f, 0.f, 0.f, 0.f};
    float ssq = 0.f;

    for (int n = blockIdx.x; n < N; n += gridDim.x) {
        const float f = F[n * 16 + k];
        const float4* hrow = reinterpret_cast<const float4*>(h + n * 128) + dg * 2;
        const float4 a = hrow[0];
        const float4 b = hrow[1];
        acc[0] += a.x * f; acc[1] += a.y * f; acc[2] += a.z * f; acc[3] += a.w * f;
        acc[4] += b.x * f; acc[5] += b.y * f; acc[6] += b.z * f; acc[7] += b.w * f;
        if (k == 0) {
            ssq += a.x * a.x + a.y * a.y + a.z * a.z + a.w * a.w
                 + b.x * b.x + b.y * b.y + b.z * b.z + b.w * b.w;
        }
    }

    // Each thread owns 8 unique (d,k) cells of M -> direct atomic accumulate.
    const int d0 = dg * 8;
    #pragma unroll
    for (int j = 0; j < 8; ++j) {
        atomicAdd(&ws[(d0 + j) * 16 + k], acc[j]);
    }

    // ssq: only k==0 lanes hold nonzero; butterfly across the 64-lane wave.
    #pragma unroll
    for (int off = 32; off > 0; off >>= 1) {
        ssq += __shfl_down(ssq, off);
    }
    if ((t & 63) == 0) {
        atomicAdd(&ws[2048], ssq);
    }
}

__global__ __launch_bounds__(256) void kmeans_finish(
    const float* __restrict__ ws, float* __restrict__ out) {
    const int t = threadIdx.x;  // 256 threads, each owns 8 M cells
    float s = 0.f;
    #pragma unroll
    for (int j = 0; j < 8; ++j) {
        const float m = ws[t * 8 + j];
        s += m * m;
    }
    #pragma unroll
    for (int off = 32; off > 0; off >>= 1) {
        s += __shfl_down(s, off);
    }
    __shared__ float red[4];
    if ((t & 63) == 0) red[t >> 6] = s;
    __syncthreads();
    if (t == 0) {
        const float sm2 = red[0] + red[1] + red[2] + red[3];
        out[0] = ws[2048] - sm2;  // hard write: d_out is poisoned每 replay
    }
}

extern "C" void kernel_launch(void* const* d_in, const int* in_sizes, int n_in,
                              void* d_out, int out_size, void* d_ws, size_t ws_size,
                              hipStream_t stream) {
    const float* h = (const float*)d_in[0];  // [N,128] f32
    const float* F = (const float*)d_in[1];  // [N,16]  f32
    float* out = (float*)d_out;              // scalar f32
    float* ws  = (float*)d_ws;

    const int N = in_sizes[0] / 128;

    // Zero M accumulators + ssq (ws is poisoned to 0xAA before every launch).
    hipMemsetAsync(ws, 0, 2049 * sizeof(float), stream);

    kmeans_partial<<<GA, 256, 0, stream>>>(h, F, ws, N);
    kmeans_finish<<<1, 256, 0, stream>>>(ws, out);
}